// Round 4
// baseline (509.588 us; speedup 1.0000x reference)
//
#include <hip/hip_runtime.h>
#include <hip/hip_bf16.h>

// MultisenseLearner: out[b] = logsumexp_{s,t}( sum_d W[j,d,s]*V[i,d,t] + wb[j,s] + vb[i,t] )
// V,W: (50000,300,4) f32; vb,wb: (50000,4) f32; IJ: (100000,2) int; out: (100000,) f32.
//
// R3 finding: compiler sank the gathers (VGPR=32 -> ~2 loads in flight/wave ->
// latency-bound at 2.6 TB/s, VALUBusy 20%). R4 change: sched_barrier(0) pins
// all 10 float4 row-gathers + 2 bias loads BEFORE any FMA; launch_bounds(256,4)
// raises the VGPR budget to 128 so the allocator can keep them live.

constexpr int D   = 300;
constexpr int NS  = 4;
constexpr int ROW = D * NS;   // 1200 floats per gathered row

__global__ __launch_bounds__(256, 4) void multisense_kernel(
    const float* __restrict__ V,
    const float* __restrict__ W,
    const float* __restrict__ vb,
    const float* __restrict__ wb,
    const unsigned int* __restrict__ IJw,   // raw 32-bit view of IJ
    float* __restrict__ out,
    int B)
{
    const int lane = threadIdx.x & 63;
    const int b    = blockIdx.x * (blockDim.x >> 6) + (threadIdx.x >> 6);
    if (b >= B) return;   // wave-uniform; grid covers B exactly

    // --- int64-vs-int32 detection (per wave, data-deterministic) ---
    // Indices < 50000 < 2^31, so int64 data has every odd 32-bit word == 0.
    unsigned int probe = (lane < 32) ? IJw[2 * lane + 1] : 0u;
    const bool isI64 = (__ballot(probe != 0u) == 0ull);

    int i, j;
    if (isI64) { i = (int)IJw[4 * (size_t)b]; j = (int)IJw[4 * (size_t)b + 2]; }
    else       { i = (int)IJw[2 * (size_t)b]; j = (int)IJw[2 * (size_t)b + 1]; }

    const float* __restrict__ Vr = V + (size_t)i * ROW;
    const float* __restrict__ Wr = W + (size_t)j * ROW;

    // Epilogue ownership: lane ends up holding the d-sum for sense pair
    // s=(lane>>4)&3, t=(lane>>2)&3 after the splitting reduction.
    const int s_idx = (lane >> 4) & 3;
    const int t_idx = (lane >> 2) & 3;

    // --- issue ALL loads, pinned before compute by sched_barrier ---
    const float wbj = wb[(size_t)j * NS + s_idx];
    const float vbi = vb[(size_t)i * NS + t_idx];

    // tail mask for chunk 4: d = 256+lane valid for lanes 0..43 (D=300)
    const int   d4 = 256 + lane;
    const int   dc = (d4 < D) ? d4 : 0;      // clamp to stay in-row
    const float tm = (d4 < D) ? 1.0f : 0.0f;

    float4 va0 = *reinterpret_cast<const float4*>(Vr + (size_t)(lane      ) * NS);
    float4 wa0 = *reinterpret_cast<const float4*>(Wr + (size_t)(lane      ) * NS);
    float4 va1 = *reinterpret_cast<const float4*>(Vr + (size_t)(lane +  64) * NS);
    float4 wa1 = *reinterpret_cast<const float4*>(Wr + (size_t)(lane +  64) * NS);
    float4 va2 = *reinterpret_cast<const float4*>(Vr + (size_t)(lane + 128) * NS);
    float4 wa2 = *reinterpret_cast<const float4*>(Wr + (size_t)(lane + 128) * NS);
    float4 va3 = *reinterpret_cast<const float4*>(Vr + (size_t)(lane + 192) * NS);
    float4 wa3 = *reinterpret_cast<const float4*>(Wr + (size_t)(lane + 192) * NS);
    float4 va4 = *reinterpret_cast<const float4*>(Vr + (size_t)dc * NS);
    float4 wa4 = *reinterpret_cast<const float4*>(Wr + (size_t)dc * NS);

    // Nothing may move across this: all 10 vmem gathers are now outstanding.
    __builtin_amdgcn_sched_barrier(0);

    float acc[16];
#pragma unroll
    for (int m = 0; m < 16; ++m) acc[m] = 0.0f;

#define GRAM(vv, ww)                                                          \
    do {                                                                      \
        const float v0 = (vv).x, v1 = (vv).y, v2 = (vv).z, v3 = (vv).w;       \
        const float w0 = (ww).x, w1 = (ww).y, w2 = (ww).z, w3 = (ww).w;       \
        acc[ 0] = fmaf(w0, v0, acc[ 0]); acc[ 1] = fmaf(w0, v1, acc[ 1]);     \
        acc[ 2] = fmaf(w0, v2, acc[ 2]); acc[ 3] = fmaf(w0, v3, acc[ 3]);     \
        acc[ 4] = fmaf(w1, v0, acc[ 4]); acc[ 5] = fmaf(w1, v1, acc[ 5]);     \
        acc[ 6] = fmaf(w1, v2, acc[ 6]); acc[ 7] = fmaf(w1, v3, acc[ 7]);     \
        acc[ 8] = fmaf(w2, v0, acc[ 8]); acc[ 9] = fmaf(w2, v1, acc[ 9]);     \
        acc[10] = fmaf(w2, v2, acc[10]); acc[11] = fmaf(w2, v3, acc[11]);     \
        acc[12] = fmaf(w3, v0, acc[12]); acc[13] = fmaf(w3, v1, acc[13]);     \
        acc[14] = fmaf(w3, v2, acc[14]); acc[15] = fmaf(w3, v3, acc[15]);     \
    } while (0)

    GRAM(va0, wa0);
    GRAM(va1, wa1);
    GRAM(va2, wa2);
    GRAM(va3, wa3);
    // tail chunk: zero the W side for masked lanes
    wa4.x *= tm; wa4.y *= tm; wa4.z *= tm; wa4.w *= tm;
    GRAM(va4, wa4);
#undef GRAM

    // --- value-splitting wave reduction: 16 vals -> 1 val/lane in 4 steps ---
    const bool b5 = (lane & 32) != 0;
    float r8[8];
#pragma unroll
    for (int m = 0; m < 8; ++m) {
        const float send = b5 ? acc[m]     : acc[m + 8];
        const float keep = b5 ? acc[m + 8] : acc[m];
        r8[m] = keep + __shfl_xor(send, 32, 64);
    }
    const bool b4 = (lane & 16) != 0;
    float r4[4];
#pragma unroll
    for (int m = 0; m < 4; ++m) {
        const float send = b4 ? r8[m]     : r8[m + 4];
        const float keep = b4 ? r8[m + 4] : r8[m];
        r4[m] = keep + __shfl_xor(send, 16, 64);
    }
    const bool b3 = (lane & 8) != 0;
    float r2[2];
#pragma unroll
    for (int m = 0; m < 2; ++m) {
        const float send = b3 ? r4[m]     : r4[m + 2];
        const float keep = b3 ? r4[m + 2] : r4[m];
        r2[m] = keep + __shfl_xor(send, 8, 64);
    }
    const bool b2 = (lane & 4) != 0;
    float r1;
    {
        const float send = b2 ? r2[0] : r2[1];
        const float keep = b2 ? r2[1] : r2[0];
        r1 = keep + __shfl_xor(send, 4, 64);
    }
    // finish the d-sum across lane bits 1:0 (same sense-pair class)
    r1 += __shfl_xor(r1, 2, 64);
    r1 += __shfl_xor(r1, 1, 64);

    // --- epilogue: one exp per lane, reduce the 16 classes ---
    float e = expf(r1 + wbj + vbi);
    e += __shfl_xor(e,  4, 64);
    e += __shfl_xor(e,  8, 64);
    e += __shfl_xor(e, 16, 64);
    e += __shfl_xor(e, 32, 64);

    if (lane == 0) out[b] = logf(e);
}

extern "C" void kernel_launch(void* const* d_in, const int* in_sizes, int n_in,
                              void* d_out, int out_size, void* d_ws, size_t ws_size,
                              hipStream_t stream) {
    const float* V  = (const float*)d_in[0];
    const float* W  = (const float*)d_in[1];
    const float* vb = (const float*)d_in[2];
    const float* wb = (const float*)d_in[3];
    const unsigned int* IJ = (const unsigned int*)d_in[4];
    float* out = (float*)d_out;

    const int B = out_size;                  // one output per batch element
    const int wavesPerBlock = 4;             // 256 threads
    dim3 block(256);
    dim3 grid((B + wavesPerBlock - 1) / wavesPerBlock);
    hipLaunchKernelGGL(multisense_kernel, grid, block, 0, stream,
                       V, W, vb, wb, IJ, out, B);
}